// Round 13
// baseline (263.718 us; speedup 1.0000x reference)
//
#include <hip/hip_runtime.h>

#define EXPN 4
#define CAP 48
#define NSLOT 192   // EXPN*CAP
#define NBLK 4

// transformed-weight layout (bf16), per expert:
#define OFF_RB1 0         // + i*9216
#define OFF_RB2 36864     // + i*9216
#define OFF_END 73728
#define OFF_UP1 82944
#define OFF_UP2 119808
#define OFF_TAIL 156672
#define PER_E 157536

typedef __attribute__((ext_vector_type(8))) short bf16x8;
typedef __attribute__((ext_vector_type(4))) float f32x4;

static __device__ __forceinline__ float bf2f(unsigned short s) {
  union { unsigned u; float f; } c; c.u = ((unsigned)s) << 16; return c.f;
}
static __device__ __forceinline__ unsigned short f2bf(float f) {
  union { float f; unsigned u; } c; c.f = f;
  unsigned u = c.u;
  return (unsigned short)((u + 0x7fffu + ((u >> 16) & 1u)) >> 16);  // RNE
}
static __device__ __forceinline__ f32x4 mfma16(bf16x8 a, bf16x8 b, f32x4 c) {
  return __builtin_amdgcn_mfma_f32_16x16x32_bf16(a, b, c, 0, 0, 0);
}
static __device__ __forceinline__ float relu_f(float x) { return fmaxf(x, 0.f); }

// LDS channel-last swizzle: pixel p, 16B-slot s (0..3) -> shorts offset.
// Shift-invariance: (Dp>>1)%4==0  =>  swz(p+Dp,s) == swz(p,s) + Dp*32.
static __device__ __forceinline__ unsigned swz(unsigned p, unsigned s) {
  return p * 32 + ((s ^ ((p >> 1) & 3u)) * 8);
}
// signed variant (bases may be formally negative before adding static offsets)
static __device__ __forceinline__ int swzI(int p, int s) {
  return p * 32 + ((s ^ ((p >> 1) & 3)) * 8);
}

// ---------------- classifier stage A ----------------
__global__ __launch_bounds__(256) void k_cls_conv(
    const float* __restrict__ x, const float* __restrict__ cw,
    const float* __restrict__ cb, float* __restrict__ part) {
  int n = blockIdx.y, band = blockIdx.x, t = threadIdx.x;
  int og = t >> 6, r = (t >> 3) & 7, cg = t & 7;
  int c0 = cg * 4;
  __shared__ float wl[3 * 32 * 9];
  __shared__ float tile[3 * 10 * 34];
  for (int k = t; k < 864; k += 256) {
    int o = k / 27;
    int rem = k % 27;
    int ci = rem / 9, tap = rem % 9;
    wl[(ci * 32 + o) * 9 + tap] = cw[k];
  }
  const float* inb = x + (size_t)n * 3072;
  for (int k = t; k < 1020; k += 256) {
    int ci = k / 340;
    int rem = k % 340;
    int lr = rem / 34, lc = rem % 34;
    int gr = band * 8 - 1 + lr, gc = lc - 1;
    float v = 0.f;
    if (gr >= 0 && gr < 32 && gc >= 0 && gc < 32) v = inb[(ci * 32 + gr) * 32 + gc];
    tile[k] = v;
  }
  __syncthreads();
  float acc[8][4];
#pragma unroll
  for (int oi = 0; oi < 8; ++oi) {
    float b = cb[og * 8 + oi];
#pragma unroll
    for (int p = 0; p < 4; ++p) acc[oi][p] = b;
  }
#pragma unroll
  for (int ci = 0; ci < 3; ++ci) {
    float iv[3][6];
#pragma unroll
    for (int ky = 0; ky < 3; ++ky)
#pragma unroll
      for (int dx = 0; dx < 6; ++dx)
        iv[ky][dx] = tile[ci * 340 + (r + ky) * 34 + c0 + dx];
#pragma unroll
    for (int oi = 0; oi < 8; ++oi) {
      const float* w9 = &wl[((size_t)ci * 32 + og * 8 + oi) * 9];
#pragma unroll
      for (int ky = 0; ky < 3; ++ky)
#pragma unroll
        for (int kx = 0; kx < 3; ++kx) {
          float wv = w9[ky * 3 + kx];
#pragma unroll
          for (int p = 0; p < 4; ++p) acc[oi][p] += wv * iv[ky][p + kx];
        }
    }
  }
#pragma unroll
  for (int oi = 0; oi < 8; ++oi) {
    float s = relu_f(acc[oi][0]) + relu_f(acc[oi][1]) + relu_f(acc[oi][2]) + relu_f(acc[oi][3]);
#pragma unroll
    for (int off = 32; off >= 1; off >>= 1) s += __shfl_down(s, off, 64);
    if ((t & 63) == 0) part[((size_t)n * 4 + band) * 32 + og * 8 + oi] = s;
  }
}

// ---------------- score + route + zero-unrouted (fused, 1 block) ----------------
__global__ __launch_bounds__(256) void k_score_route(
    const float* __restrict__ part, const float* __restrict__ fw,
    const float* __restrict__ fb, int* __restrict__ slot_img,
    float* __restrict__ out, int N) {
  __shared__ int assign_s[256];
  __shared__ unsigned char routed_s[256];
  int t = threadIdx.x;
  routed_s[t] = 0;
  for (int n = t; n < N; n += 256) {
    float cm[32];
#pragma unroll
    for (int o = 0; o < 32; ++o) {
      float s = part[((size_t)n * 4 + 0) * 32 + o] + part[((size_t)n * 4 + 1) * 32 + o] +
                part[((size_t)n * 4 + 2) * 32 + o] + part[((size_t)n * 4 + 3) * 32 + o];
      cm[o] = s * (1.f / 1024.f);
    }
    float best = -1e30f;
    int bi = 0;
    for (int e = 0; e < EXPN; ++e) {
      float sc = fb[e];
#pragma unroll
      for (int o = 0; o < 32; ++o) sc += cm[o] * fw[e * 32 + o];
      if (sc > best) { best = sc; bi = e; }
    }
    assign_s[n] = bi;
  }
  __syncthreads();
  if (t == 0) {
    int cnt[EXPN];
    for (int e = 0; e < EXPN; ++e) cnt[e] = 0;
    for (int k = 0; k < NSLOT; ++k) slot_img[k] = -1;
    for (int n = 0; n < N; ++n) {
      int e = assign_s[n];
      if (cnt[e] < CAP) { slot_img[e * CAP + cnt[e]] = n; cnt[e]++; routed_s[n] = 1; }
    }
  }
  __syncthreads();
  // zero only unrouted images (typically none) — replaces the blanket 25MB zero
  for (int n = 0; n < N; ++n) {
    if (!routed_s[n]) {
      float4* o = (float4*)(out + (size_t)n * 49152);
      for (int i = t; i < 12288; i += 256) o[i] = make_float4(0.f, 0.f, 0.f, 0.f);
    }
  }
}

// ---------------- head: wxform prologue + conv 3->32 fp32 VALU -> h (bf16 ch-last) ----------------
__global__ __launch_bounds__(256) void k_head(
    const float* __restrict__ x, unsigned short* __restrict__ hbuf,
    const float* __restrict__ wglob, const float* __restrict__ bglob,
    const int* __restrict__ slot_img,
    const float* __restrict__ rb_w1, const float* __restrict__ rb_w2,
    const float* __restrict__ end_w, const float* __restrict__ up_w1,
    const float* __restrict__ up_w2, const float* __restrict__ tail_w,
    unsigned short* __restrict__ wt) {
  int slot = blockIdx.y;
  int band = blockIdx.x;
  int t = threadIdx.x;
  // --- wxform prologue (grid-stride over all weight elements) ---
  {
    int bid = blockIdx.y * 4 + blockIdx.x;
    for (int idx = bid * 256 + t; idx < EXPN * PER_E; idx += 768 * 256) {
      int e = idx / PER_E, r = idx % PER_E;
      const float* src;
      int c, OC;
      if (r < OFF_RB2) {
        int i = r / 9216; c = r % 9216; OC = 32;
        src = rb_w1 + ((size_t)e * NBLK + i) * 9216;
      } else if (r < OFF_END) {
        int i = (r - OFF_RB2) / 9216; c = (r - OFF_RB2) % 9216; OC = 32;
        src = rb_w2 + ((size_t)e * NBLK + i) * 9216;
      } else if (r < OFF_UP1) {
        c = r - OFF_END; OC = 32;
        src = end_w + (size_t)e * 9216;
      } else if (r < OFF_UP2) {
        c = r - OFF_UP1; OC = 128;
        src = up_w1 + (size_t)e * 36864;
      } else if (r < OFF_TAIL) {
        c = r - OFF_UP2; OC = 128;
        src = up_w2 + (size_t)e * 36864;
      } else {
        c = r - OFF_TAIL; OC = 3;
        src = tail_w + (size_t)e * 864;
      }
      int tap = c / (OC * 32);
      int rem = c % (OC * 32);
      int och = rem / 32, ich = rem % 32;
      wt[idx] = f2bf(src[(och * 32 + ich) * 9 + tap]);
    }
  }
  int img = slot_img[slot];
  if (img < 0) return;
  int e = slot / CAP;
  int og = t >> 6, r = (t >> 3) & 7, cg = t & 7;
  int c0 = cg * 4;
  __shared__ float wl[3 * 32 * 9];
  __shared__ float tile[3 * 10 * 34];
  __shared__ __align__(16) unsigned short ostg[256 * 32];
  const float* wsrc = wglob + (size_t)e * 32 * 27;
  for (int k = t; k < 864; k += 256) {
    int o = k / 27;
    int rem = k % 27;
    int ci = rem / 9, tap = rem % 9;
    wl[(ci * 32 + o) * 9 + tap] = wsrc[k];
  }
  const float* bsrc = bglob + (size_t)e * 32;
  const float* inb = x + (size_t)img * 3072;
  for (int k = t; k < 3 * 10 * 34; k += 256) {
    int ci = k / 340;
    int rem = k % 340;
    int lr = rem / 34, lc = rem % 34;
    int gr = band * 8 - 1 + lr, gc = lc - 1;
    float v = 0.f;
    if (gr >= 0 && gr < 32 && gc >= 0 && gc < 32) v = inb[(ci * 32 + gr) * 32 + gc];
    tile[k] = v;
  }
  __syncthreads();
  float acc[8][4];
#pragma unroll
  for (int oi = 0; oi < 8; ++oi) {
    float b = bsrc[og * 8 + oi];
#pragma unroll
    for (int p = 0; p < 4; ++p) acc[oi][p] = b;
  }
#pragma unroll
  for (int ci = 0; ci < 3; ++ci) {
    float iv[3][6];
#pragma unroll
    for (int ky = 0; ky < 3; ++ky)
#pragma unroll
      for (int dx = 0; dx < 6; ++dx)
        iv[ky][dx] = tile[ci * 340 + (r + ky) * 34 + c0 + dx];
#pragma unroll
    for (int oi = 0; oi < 8; ++oi) {
      const float* w9 = &wl[((size_t)ci * 32 + og * 8 + oi) * 9];
#pragma unroll
      for (int ky = 0; ky < 3; ++ky)
#pragma unroll
        for (int kx = 0; kx < 3; ++kx) {
          float wv = w9[ky * 3 + kx];
#pragma unroll
          for (int p = 0; p < 4; ++p) acc[oi][p] += wv * iv[ky][p + kx];
        }
    }
  }
#pragma unroll
  for (int oi = 0; oi < 8; ++oi)
#pragma unroll
    for (int p = 0; p < 4; ++p)
      ostg[(r * 32 + c0 + p) * 32 + og * 8 + oi] = f2bf(acc[oi][p]);
  __syncthreads();
  for (int u = t; u < 1024; u += 256) {
    int px = u >> 2, c8 = (u & 3) * 8;
    int4 v = *(const int4*)&ostg[px * 32 + c8];
    size_t gi = ((size_t)slot * 1024 + band * 256 + px) * 32 + c8;
    *(int4*)&hbuf[gi] = v;
  }
}

// ---------------- body conv32 helper: swizzled LDS, PRECOMPUTED addresses ----------------
template <int EPI>
static __device__ __forceinline__ void conv32_lds8(
    const unsigned short* __restrict__ srcP, unsigned short* __restrict__ dstP,
    const unsigned short* __restrict__ hb,
    const unsigned short* __restrict__ wtc, const float* __restrict__ bsrc,
    const int (&rdA)[6][3], const int (&wrA)[4][2],
    int w, int l, int col, int s4) {
  bf16x8 Bf[9][2];
  f32x4 bias4[2];
#pragma unroll
  for (int n = 0; n < 2; ++n) {
    bias4[n] = *(const f32x4*)&bsrc[n * 16 + s4 * 4];
#pragma unroll
    for (int tap = 0; tap < 9; ++tap)
      Bf[tap][n] = *(const bf16x8*)&wtc[((tap * 32) + n * 16 + col) * 32 + s4 * 8];
  }
  int rbase = w * 4;
#pragma unroll
  for (int xh = 0; xh < 2; ++xh) {
    bf16x8 Af[6][3];
#pragma unroll
    for (int rr = 0; rr < 6; ++rr)
#pragma unroll
      for (int kx = 0; kx < 3; ++kx)
        Af[rr][kx] = *(const bf16x8*)&srcP[rdA[rr][kx] + xh * 512];
    f32x4 acc[4][2];
#pragma unroll
    for (int m = 0; m < 4; ++m)
#pragma unroll
      for (int n = 0; n < 2; ++n) acc[m][n] = bias4[n];
    __builtin_amdgcn_s_setprio(1);
#pragma unroll
    for (int ky = 0; ky < 3; ++ky)
#pragma unroll
      for (int kx = 0; kx < 3; ++kx)
#pragma unroll
        for (int r = 0; r < 4; ++r)
#pragma unroll
          for (int n = 0; n < 2; ++n)
            acc[r][n] = mfma16(Bf[ky * 3 + kx][n], Af[r + ky][kx], acc[r][n]);
    __builtin_amdgcn_s_setprio(0);
#pragma unroll
    for (int r = 0; r < 4; ++r) {
      int row = rbase + r;
      int x = xh * 16 + col;
#pragma unroll
      for (int n = 0; n < 2; ++n) {
        unsigned li = (unsigned)(wrA[r][n] + xh * 512);
        float v0 = acc[r][n][0], v1 = acc[r][n][1], v2 = acc[r][n][2], v3 = acc[r][n][3];
        if (EPI == 0) {
          v0 = relu_f(v0); v1 = relu_f(v1); v2 = relu_f(v2); v3 = relu_f(v3);
        } else if (EPI == 1) {
          uint2 old = *(const uint2*)&dstP[li];
          v0 = bf2f((unsigned short)(old.x & 0xffff)) + 0.1f * v0;
          v1 = bf2f((unsigned short)(old.x >> 16)) + 0.1f * v1;
          v2 = bf2f((unsigned short)(old.y & 0xffff)) + 0.1f * v2;
          v3 = bf2f((unsigned short)(old.y >> 16)) + 0.1f * v3;
        } else if (EPI == 2) {
          uint2 hv = *(const uint2*)&hb[((unsigned)(row * 32 + x)) * 32 + n * 16 + s4 * 4];
          v0 += bf2f((unsigned short)(hv.x & 0xffff));
          v1 += bf2f((unsigned short)(hv.x >> 16));
          v2 += bf2f((unsigned short)(hv.y & 0xffff));
          v3 += bf2f((unsigned short)(hv.y >> 16));
        }
        uint2 o;
        o.x = (unsigned)f2bf(v0) | ((unsigned)f2bf(v1) << 16);
        o.y = (unsigned)f2bf(v2) | ((unsigned)f2bf(v3) << 16);
        *(uint2*)&dstP[li] = o;
      }
    }
  }
}

// ---------------- body mega-kernel: 4 ResBlocks + end(+h) + up1, all in LDS ----------------
__global__ __launch_bounds__(512, 1) void k_body(
    const unsigned short* __restrict__ hbuf, unsigned short* __restrict__ u1,
    const unsigned short* __restrict__ wt,
    const float* __restrict__ rb_b1, const float* __restrict__ rb_b2,
    const float* __restrict__ end_b, const float* __restrict__ up_b1,
    const int* __restrict__ slot_img) {
  int slot = blockIdx.x;
  int img = slot_img[slot];
  if (img < 0) return;
  int e = slot / CAP;
  int t = threadIdx.x;
  int w = t >> 6, l = t & 63;
  int col = l & 15, s4 = l >> 4;

  __shared__ __align__(16) unsigned short resP[34 * 34 * 32];
  __shared__ __align__(16) unsigned short tP[34 * 34 * 32];
  __shared__ __align__(16) unsigned short scr[8 * 512];

  int rdA[6][3];
  int wrA[4][2];
#pragma unroll
  for (int rr = 0; rr < 6; ++rr)
#pragma unroll
    for (int kx = 0; kx < 3; ++kx)
      rdA[rr][kx] = (int)swz((unsigned)((w * 4 + rr) * 34 + col + kx), (unsigned)s4);
#pragma unroll
  for (int r = 0; r < 4; ++r)
#pragma unroll
    for (int n = 0; n < 2; ++n)
      wrA[r][n] = (int)(swz((unsigned)((w * 4 + r + 1) * 34 + col + 1),
                            (unsigned)(n * 2 + (s4 >> 1))) + (s4 & 1) * 4);

  int4 z = make_int4(0, 0, 0, 0);
  for (int u = t; u < 4624; u += 512) {
    *(int4*)&resP[u * 8] = z;
    *(int4*)&tP[u * 8] = z;
  }
  __syncthreads();
  const unsigned short* hsl = hbuf + (size_t)slot * 32768;
  for (int u = t; u < 4096; u += 512) {
    int px = u >> 2, sl = u & 3;
    unsigned p = (unsigned)(((px >> 5) + 1) * 34 + (px & 31) + 1);
    *(int4*)&resP[swz(p, sl)] = *(const int4*)&hsl[px * 32 + sl * 8];
  }
  __syncthreads();

  unsigned short* wscr = &scr[w * 512];
  const unsigned short* wte = wt + (size_t)e * PER_E;

  for (int i = 0; i < NBLK; ++i) {
    conv32_lds8<0>(resP, tP, nullptr, wte + OFF_RB1 + i * 9216,
                   rb_b1 + (size_t)e * NBLK * 32 + i * 32, rdA, wrA, w, l, col, s4);
    __syncthreads();
    conv32_lds8<1>(tP, resP, nullptr, wte + OFF_RB2 + i * 9216,
                   rb_b2 + (size_t)e * NBLK * 32 + i * 32, rdA, wrA, w, l, col, s4);
    __syncthreads();
  }
  conv32_lds8<2>(resP, tP, hsl, wte + OFF_END, end_b + (size_t)e * 32, rdA, wrA,
                 w, l, col, s4);
  __syncthreads();

  // up1: conv 32->128 + pixel shuffle -> u1 [slot][64][64][32]
  {
    int og = w >> 1, rh = w & 1;
    const unsigned short* wtc = wte + OFF_UP1;
    const float* bsrc = up_b1 + (size_t)e * 128;
    bf16x8 Bf[9][2];
    float bias[2];
#pragma unroll
    for (int n = 0; n < 2; ++n) {
      int och = og * 32 + n * 16 + col;
      bias[n] = bsrc[och];
#pragma unroll
      for (int tap = 0; tap < 9; ++tap)
        Bf[tap][n] = *(const bf16x8*)&wtc[((tap * 128) + och) * 32 + s4 * 8];
    }
    unsigned short* u1g = u1 + (size_t)slot * 64 * 64 * 32;
#pragma unroll
    for (int xh = 0; xh < 2; ++xh) {
      int x0 = xh * 16;
#pragma unroll
      for (int rg = 0; rg < 4; ++rg) {
        int rbase = rh * 16 + rg * 4;
        bf16x8 Af[6][3];
#pragma unroll
        for (int rr = 0; rr < 6; ++rr)
#pragma unroll
          for (int kx = 0; kx < 3; ++kx)
            Af[rr][kx] = *(const bf16x8*)&tP[swz((rbase + rr) * 34 + x0 + col + kx, s4)];
        f32x4 acc[4][2];
#pragma unroll
        for (int m = 0; m < 4; ++m)
#pragma unroll
          for (int n = 0; n < 2; ++n) acc[m][n] = (f32x4){bias[n], bias[n], bias[n], bias[n]};
        __builtin_amdgcn_s_setprio(1);
#pragma unroll
        for (int ky = 0; ky < 3; ++ky)
#pragma unroll
          for (int kx = 0; kx < 3; ++kx)
#pragma unroll
            for (int r = 0; r < 4; ++r)
#pragma unroll
              for (int n = 0; n < 2; ++n)
                acc[r][n] = mfma16(Af[r + ky][kx], Bf[ky * 3 + kx][n], acc[r][n]);
        __builtin_amdgcn_s_setprio(0);
#pragma unroll
        for (int r = 0; r < 4; ++r) {
          int row = rbase + r;
#pragma unroll
          for (int n = 0; n < 2; ++n) {
            int och = og * 32 + n * 16 + col;
            int ryrx = och & 3, ccl = (och >> 2) & 7;
#pragma unroll
            for (int reg = 0; reg < 4; ++reg)
              wscr[(ryrx * 16 + s4 * 4 + reg) * 8 + ccl] = f2bf(acc[r][n][reg]);
          }
          int ryrx2 = l >> 4, px2 = l & 15;
          int4 yv = *(const int4*)&wscr[(ryrx2 * 16 + px2) * 8];
          int ry = ryrx2 >> 1, rx = ryrx2 & 1;
          int oy = 2 * row + ry, ox = 2 * (x0 + px2) + rx;
          *(int4*)&u1g[((size_t)oy * 64 + ox) * 32 + og * 8] = yv;
        }
      }
    }
  }
}

// ---------------- fused up2 + tail v3: all LDS addresses precomputed ----------------
__global__ __launch_bounds__(256) void k_uptail(
    const unsigned short* __restrict__ u1, float* __restrict__ out,
    const unsigned short* __restrict__ wt, const float* __restrict__ up_b2,
    const float* __restrict__ tail_b, const int* __restrict__ slot_img) {
  int slot = blockIdx.y;
  int img = slot_img[slot];
  if (img < 0) return;
  int e = slot / CAP;
  int b = blockIdx.x & 15;
  int xh2 = blockIdx.x >> 4;
  int t = threadIdx.x;
  int w = t >> 6, l = t & 63;
  int col = l & 15, s4 = l >> 4;

  __shared__ __align__(16) unsigned short u1t[8 * 36 * 32];
  __shared__ __align__(16) unsigned short u2t[10 * 66 * 32];

  // ---- precomputed addresses (swz shift-invariance: (Dp>>1)%4==0) ----
  // up2 Af reads: p = row*36 + xg*16 + col + kx ; addr = rdU[row&1][kx] + (row>>1)*2304 + xg*512
  int rdU[2][3];
#pragma unroll
  for (int rp = 0; rp < 2; ++rp)
#pragma unroll
    for (int kx = 0; kx < 3; ++kx)
      rdU[rp][kx] = (int)swz((unsigned)(rp * 36 + col + kx), (unsigned)s4);
  // u2t stores: p = (2*yy+ry-1)*66 + 2*col + rx - 1 ; addr = stB[yy&1][n][reg] + (yy>>1)*8448 + xg*1024
  int stB[2][2][4];
#pragma unroll
  for (int yp = 0; yp < 2; ++yp)
#pragma unroll
    for (int n = 0; n < 2; ++n)
#pragma unroll
      for (int reg = 0; reg < 4; ++reg) {
        int ry = reg >> 1, rx = reg & 1;
        int pb = (2 * yp + ry - 1) * 66 + 2 * col + rx - 1;
        stB[yp][n][reg] = swzI(pb, w) + n * 4 + s4;
      }
  // tail reads: p = (w*2+rr)*66 + gx*16 + col + kx ; addr = rdT[rr][kx] + gx*512
  int rdT[4][3];
#pragma unroll
  for (int rr = 0; rr < 4; ++rr)
#pragma unroll
    for (int kx = 0; kx < 3; ++kx)
      rdT[rr][kx] = (int)swz((unsigned)((w * 2 + rr) * 66 + col + kx), (unsigned)s4);

  // stage u1 tile: rows 4b-2..4b+5, cols 32*xh2-2..+33
  const unsigned short* u1s = u1 + (size_t)slot * 64 * 64 * 32;
  int r0 = 4 * b - 2, c0g = 32 * xh2 - 2;
  for (int u = t; u < 8 * 36 * 4; u += 256) {
    int rr = u / 144;
    int rem = u - rr * 144;
    int cc = rem >> 2, sl = rem & 3;
    int gy = r0 + rr, gx = c0g + cc;
    int4 v = make_int4(0, 0, 0, 0);
    if (gy >= 0 && gy < 64 && gx >= 0 && gx < 64)
      v = *(const int4*)&u1s[((size_t)gy * 64 + gx) * 32 + sl * 8];
    *(int4*)&u1t[swz((unsigned)(rr * 36 + cc), sl)] = v;
  }

  // up2 weights + bias (swapped form)
  const unsigned short* wtc = wt + (size_t)e * PER_E + OFF_UP2;
  bf16x8 Bf[9][2];
  f32x4 bias4[2];
#pragma unroll
  for (int n = 0; n < 2; ++n) {
    bias4[n] = *(const f32x4*)&up_b2[(size_t)e * 128 + w * 32 + n * 16 + s4 * 4];
#pragma unroll
    for (int tap = 0; tap < 9; ++tap)
      Bf[tap][n] = *(const bf16x8*)&wtc[((tap * 128) + w * 32 + n * 16 + col) * 32 + s4 * 8];
  }
  // tail weights
  const unsigned short* wtt = wt + (size_t)e * PER_E + OFF_TAIL;
  bf16x8 Bt[9];
  float biast = 0.f;
  if (col < 3) biast = tail_b[e * 3 + col];
#pragma unroll
  for (int tap = 0; tap < 9; ++tap) {
    if (col < 3)
      Bt[tap] = *(const bf16x8*)&wtt[((tap * 3) + col) * 32 + s4 * 8];
    else {
      bf16x8 bb;
#pragma unroll
      for (int j = 0; j < 8; ++j) bb[j] = (short)0;
      Bt[tap] = bb;
    }
  }
  __syncthreads();

  // up2: xg outer, yy inner with rolling 3-row Af window
#pragma unroll
  for (int xg = 0; xg < 3; ++xg) {
    bf16x8 Af[3][3];
#pragma unroll
    for (int rr = 0; rr < 3; ++rr)
#pragma unroll
      for (int kx = 0; kx < 3; ++kx)
        Af[rr][kx] = *(const bf16x8*)&u1t[rdU[rr & 1][kx] + (rr >> 1) * 2304 + xg * 512];
#pragma unroll
    for (int yy = 0; yy < 6; ++yy) {
      if (yy > 0) {
        int row = yy + 2;
#pragma unroll
        for (int kx = 0; kx < 3; ++kx)
          Af[(yy + 2) % 3][kx] =
              *(const bf16x8*)&u1t[rdU[row & 1][kx] + (row >> 1) * 2304 + xg * 512];
      }
      f32x4 acc[2];
#pragma unroll
      for (int n = 0; n < 2; ++n) acc[n] = bias4[n];
      __builtin_amdgcn_s_setprio(1);
#pragma unroll
      for (int ky = 0; ky < 3; ++ky)
#pragma unroll
        for (int kx = 0; kx < 3; ++kx)
#pragma unroll
          for (int n = 0; n < 2; ++n)
            acc[n] = mfma16(Bf[ky * 3 + kx][n], Af[(yy + ky) % 3][kx], acc[n]);
      __builtin_amdgcn_s_setprio(0);
      // stores: addr = stB + static offsets; bounds/pad folded to static+lane predicates
#pragma unroll
      for (int n = 0; n < 2; ++n)
#pragma unroll
        for (int reg = 0; reg < 4; ++reg) {
          int ry = reg >> 1, rx = reg & 1;
          if ((yy == 0 && ry == 0) || (yy == 5 && ry == 1)) continue;  // oyl out of tile
          bool valid = (xg == 1) || (xg == 0 && (col > 0 || rx == 1)) ||
                       (xg == 2 && (2 * col + rx <= 2));
          float v = acc[n][reg];
          if (b == 0 && yy == 0 && ry == 1) v = 0.f;                        // gy2 == -1
          if (b == 15 && yy == 5 && ry == 0) v = 0.f;                       // gy2 == 128
          if (xh2 == 0 && xg == 0 && col == 0 && rx == 1) v = 0.f;          // gx2 == -1
          if (xh2 == 1 && xg == 2 && col == 1 && rx == 0) v = 0.f;          // gx2 == 128
          if (valid)
            u2t[(unsigned)(stB[yy & 1][n][reg] + (yy >> 1) * 8448 + xg * 1024)] = f2bf(v);
        }
    }
  }
  __syncthreads();

  // tail: out rows 8b..8b+7, wave w does rows w*2, w*2+1; cols 64*xh2..+63
#pragma unroll
  for (int gx = 0; gx < 4; ++gx) {
    bf16x8 At[4][3];
#pragma unroll
    for (int rr = 0; rr < 4; ++rr)
#pragma unroll
      for (int kx = 0; kx < 3; ++kx)
        At[rr][kx] = *(const bf16x8*)&u2t[rdT[rr][kx] + gx * 512];
    f32x4 acc[2];
#pragma unroll
    for (int r = 0; r < 2; ++r) acc[r] = (f32x4){biast, biast, biast, biast};
    __builtin_amdgcn_s_setprio(1);
#pragma unroll
    for (int ky = 0; ky < 3; ++ky)
#pragma unroll
      for (int kx = 0; kx < 3; ++kx)
#pragma unroll
        for (int r = 0; r < 2; ++r)
          acc[r] = mfma16(At[r + ky][kx], Bt[ky * 3 + kx], acc[r]);
    __builtin_amdgcn_s_setprio(0);
    if (col < 3) {
#pragma unroll
      for (int r = 0; r < 2; ++r) {
        int grow = 8 * b + w * 2 + r;
        int gcol = 64 * xh2 + gx * 16 + s4 * 4;
        *(float4*)&out[(((size_t)img * 3 + col) * 128 + grow) * 128 + gcol] =
            make_float4(acc[r][0], acc[r][1], acc[r][2], acc[r][3]);
      }
    }
  }
}

extern "C" void kernel_launch(void* const* d_in, const int* in_sizes, int n_in,
                              void* d_out, int out_size, void* d_ws, size_t ws_size,
                              hipStream_t stream) {
  const float* inputs = (const float*)d_in[0];
  const float* cls_w = (const float*)d_in[1];
  const float* cls_b = (const float*)d_in[2];
  const float* cls_fw = (const float*)d_in[3];
  const float* cls_fb = (const float*)d_in[4];
  const float* head_w = (const float*)d_in[5];
  const float* head_b = (const float*)d_in[6];
  const float* rb_w1 = (const float*)d_in[7];
  const float* rb_b1 = (const float*)d_in[8];
  const float* rb_w2 = (const float*)d_in[9];
  const float* rb_b2 = (const float*)d_in[10];
  const float* end_w = (const float*)d_in[11];
  const float* end_b = (const float*)d_in[12];
  const float* up_w1 = (const float*)d_in[13];
  const float* up_b1 = (const float*)d_in[14];
  const float* up_w2 = (const float*)d_in[15];
  const float* up_b2 = (const float*)d_in[16];
  const float* tail_w = (const float*)d_in[17];
  const float* tail_b = (const float*)d_in[18];
  float* out = (float*)d_out;
  char* ws = (char*)d_ws;

  int N = in_sizes[0] / 3072;  // 128

  int* slot_img = (int*)(ws + 512);
  float* part = (float*)(ws + 4096);                     // [N][4][32]
  unsigned short* wt = (unsigned short*)(ws + 131072);   // 1.26 MB transformed weights
  const size_t ABUF = (size_t)NSLOT * 1024 * 32 * 2;     // 12,582,912
  size_t o_h = 1572864;
  unsigned short* h = (unsigned short*)(ws + o_h);
  unsigned short* u1 = (unsigned short*)(ws + o_h + ABUF);

  k_cls_conv<<<dim3(4, N), 256, 0, stream>>>(inputs, cls_w, cls_b, part);
  k_score_route<<<1, 256, 0, stream>>>(part, cls_fw, cls_fb, slot_img, out, N);

  k_head<<<dim3(4, NSLOT), 256, 0, stream>>>(inputs, h, head_w, head_b, slot_img,
                                             rb_w1, rb_w2, end_w, up_w1, up_w2, tail_w, wt);

  k_body<<<NSLOT, 512, 0, stream>>>(h, u1, wt, rb_b1, rb_b2, end_b, up_b1, slot_img);

  k_uptail<<<dim3(32, NSLOT), 256, 0, stream>>>(u1, out, wt, up_b2, tail_b, slot_img);
}

// Round 14
// 171.200 us; speedup vs baseline: 1.5404x; 1.5404x over previous
//
#include <hip/hip_runtime.h>

#define EXPN 4
#define CAP 48
#define NSLOT 192   // EXPN*CAP
#define NBLK 4

// transformed-weight layout (bf16), per expert:
#define OFF_RB1 0         // + i*9216
#define OFF_RB2 36864     // + i*9216
#define OFF_END 73728
#define OFF_UP1 82944
#define OFF_UP2 119808
#define OFF_TAIL 156672
#define PER_E 157536

typedef __attribute__((ext_vector_type(8))) short bf16x8;
typedef __attribute__((ext_vector_type(4))) float f32x4;

static __device__ __forceinline__ float bf2f(unsigned short s) {
  union { unsigned u; float f; } c; c.u = ((unsigned)s) << 16; return c.f;
}
static __device__ __forceinline__ unsigned short f2bf(float f) {
  union { float f; unsigned u; } c; c.f = f;
  unsigned u = c.u;
  return (unsigned short)((u + 0x7fffu + ((u >> 16) & 1u)) >> 16);  // RNE
}
static __device__ __forceinline__ f32x4 mfma16(bf16x8 a, bf16x8 b, f32x4 c) {
  return __builtin_amdgcn_mfma_f32_16x16x32_bf16(a, b, c, 0, 0, 0);
}
static __device__ __forceinline__ float relu_f(float x) { return fmaxf(x, 0.f); }

// LDS channel-last swizzle: pixel p, 16B-slot s (0..3) -> shorts offset.
// Shift-invariance: (Dp>>1)%4==0  =>  swz(p+Dp,s) == swz(p,s) + Dp*32.
static __device__ __forceinline__ unsigned swz(unsigned p, unsigned s) {
  return p * 32 + ((s ^ ((p >> 1) & 3u)) * 8);
}
static __device__ __forceinline__ int swzI(int p, int s) {
  return p * 32 + ((s ^ ((p >> 1) & 3)) * 8);
}

// ---------------- zero output (grid-wide; ~61/128 images stay zero due to CAP overflow) ----------------
__global__ void k_zero(float4* __restrict__ p, int n4) {
  int i = blockIdx.x * blockDim.x + threadIdx.x;
  int stride = gridDim.x * blockDim.x;
  for (; i < n4; i += stride) p[i] = make_float4(0.f, 0.f, 0.f, 0.f);
}

// ---------------- classifier stage A ----------------
__global__ __launch_bounds__(256) void k_cls_conv(
    const float* __restrict__ x, const float* __restrict__ cw,
    const float* __restrict__ cb, float* __restrict__ part) {
  int n = blockIdx.y, band = blockIdx.x, t = threadIdx.x;
  int og = t >> 6, r = (t >> 3) & 7, cg = t & 7;
  int c0 = cg * 4;
  __shared__ float wl[3 * 32 * 9];
  __shared__ float tile[3 * 10 * 34];
  for (int k = t; k < 864; k += 256) {
    int o = k / 27;
    int rem = k % 27;
    int ci = rem / 9, tap = rem % 9;
    wl[(ci * 32 + o) * 9 + tap] = cw[k];
  }
  const float* inb = x + (size_t)n * 3072;
  for (int k = t; k < 1020; k += 256) {
    int ci = k / 340;
    int rem = k % 340;
    int lr = rem / 34, lc = rem % 34;
    int gr = band * 8 - 1 + lr, gc = lc - 1;
    float v = 0.f;
    if (gr >= 0 && gr < 32 && gc >= 0 && gc < 32) v = inb[(ci * 32 + gr) * 32 + gc];
    tile[k] = v;
  }
  __syncthreads();
  float acc[8][4];
#pragma unroll
  for (int oi = 0; oi < 8; ++oi) {
    float b = cb[og * 8 + oi];
#pragma unroll
    for (int p = 0; p < 4; ++p) acc[oi][p] = b;
  }
#pragma unroll
  for (int ci = 0; ci < 3; ++ci) {
    float iv[3][6];
#pragma unroll
    for (int ky = 0; ky < 3; ++ky)
#pragma unroll
      for (int dx = 0; dx < 6; ++dx)
        iv[ky][dx] = tile[ci * 340 + (r + ky) * 34 + c0 + dx];
#pragma unroll
    for (int oi = 0; oi < 8; ++oi) {
      const float* w9 = &wl[((size_t)ci * 32 + og * 8 + oi) * 9];
#pragma unroll
      for (int ky = 0; ky < 3; ++ky)
#pragma unroll
        for (int kx = 0; kx < 3; ++kx) {
          float wv = w9[ky * 3 + kx];
#pragma unroll
          for (int p = 0; p < 4; ++p) acc[oi][p] += wv * iv[ky][p + kx];
        }
    }
  }
#pragma unroll
  for (int oi = 0; oi < 8; ++oi) {
    float s = relu_f(acc[oi][0]) + relu_f(acc[oi][1]) + relu_f(acc[oi][2]) + relu_f(acc[oi][3]);
#pragma unroll
    for (int off = 32; off >= 1; off >>= 1) s += __shfl_down(s, off, 64);
    if ((t & 63) == 0) part[((size_t)n * 4 + band) * 32 + og * 8 + oi] = s;
  }
}

// ---------------- score + route (fused, 1 block, no zeroing) ----------------
__global__ __launch_bounds__(256) void k_score_route(
    const float* __restrict__ part, const float* __restrict__ fw,
    const float* __restrict__ fb, int* __restrict__ slot_img, int N) {
  __shared__ int assign_s[256];
  int t = threadIdx.x;
  for (int n = t; n < N; n += 256) {
    float cm[32];
#pragma unroll
    for (int o = 0; o < 32; ++o) {
      float s = part[((size_t)n * 4 + 0) * 32 + o] + part[((size_t)n * 4 + 1) * 32 + o] +
                part[((size_t)n * 4 + 2) * 32 + o] + part[((size_t)n * 4 + 3) * 32 + o];
      cm[o] = s * (1.f / 1024.f);
    }
    float best = -1e30f;
    int bi = 0;
    for (int e = 0; e < EXPN; ++e) {
      float sc = fb[e];
#pragma unroll
      for (int o = 0; o < 32; ++o) sc += cm[o] * fw[e * 32 + o];
      if (sc > best) { best = sc; bi = e; }
    }
    assign_s[n] = bi;
  }
  __syncthreads();
  if (t == 0) {
    int cnt[EXPN];
    for (int e = 0; e < EXPN; ++e) cnt[e] = 0;
    for (int k = 0; k < NSLOT; ++k) slot_img[k] = -1;
    for (int n = 0; n < N; ++n) {
      int e = assign_s[n];
      if (cnt[e] < CAP) { slot_img[e * CAP + cnt[e]] = n; cnt[e]++; }
    }
  }
}

// ---------------- head: wxform prologue + conv 3->32 fp32 VALU -> h (bf16 ch-last) ----------------
__global__ __launch_bounds__(256) void k_head(
    const float* __restrict__ x, unsigned short* __restrict__ hbuf,
    const float* __restrict__ wglob, const float* __restrict__ bglob,
    const int* __restrict__ slot_img,
    const float* __restrict__ rb_w1, const float* __restrict__ rb_w2,
    const float* __restrict__ end_w, const float* __restrict__ up_w1,
    const float* __restrict__ up_w2, const float* __restrict__ tail_w,
    unsigned short* __restrict__ wt) {
  int slot = blockIdx.y;
  int band = blockIdx.x;
  int t = threadIdx.x;
  // --- wxform prologue (grid-stride over all weight elements) ---
  {
    int bid = blockIdx.y * 4 + blockIdx.x;
    for (int idx = bid * 256 + t; idx < EXPN * PER_E; idx += 768 * 256) {
      int e = idx / PER_E, r = idx % PER_E;
      const float* src;
      int c, OC;
      if (r < OFF_RB2) {
        int i = r / 9216; c = r % 9216; OC = 32;
        src = rb_w1 + ((size_t)e * NBLK + i) * 9216;
      } else if (r < OFF_END) {
        int i = (r - OFF_RB2) / 9216; c = (r - OFF_RB2) % 9216; OC = 32;
        src = rb_w2 + ((size_t)e * NBLK + i) * 9216;
      } else if (r < OFF_UP1) {
        c = r - OFF_END; OC = 32;
        src = end_w + (size_t)e * 9216;
      } else if (r < OFF_UP2) {
        c = r - OFF_UP1; OC = 128;
        src = up_w1 + (size_t)e * 36864;
      } else if (r < OFF_TAIL) {
        c = r - OFF_UP2; OC = 128;
        src = up_w2 + (size_t)e * 36864;
      } else {
        c = r - OFF_TAIL; OC = 3;
        src = tail_w + (size_t)e * 864;
      }
      int tap = c / (OC * 32);
      int rem = c % (OC * 32);
      int och = rem / 32, ich = rem % 32;
      wt[idx] = f2bf(src[(och * 32 + ich) * 9 + tap]);
    }
  }
  int img = slot_img[slot];
  if (img < 0) return;
  int e = slot / CAP;
  int og = t >> 6, r = (t >> 3) & 7, cg = t & 7;
  int c0 = cg * 4;
  __shared__ float wl[3 * 32 * 9];
  __shared__ float tile[3 * 10 * 34];
  __shared__ __align__(16) unsigned short ostg[256 * 32];
  const float* wsrc = wglob + (size_t)e * 32 * 27;
  for (int k = t; k < 864; k += 256) {
    int o = k / 27;
    int rem = k % 27;
    int ci = rem / 9, tap = rem % 9;
    wl[(ci * 32 + o) * 9 + tap] = wsrc[k];
  }
  const float* bsrc = bglob + (size_t)e * 32;
  const float* inb = x + (size_t)img * 3072;
  for (int k = t; k < 3 * 10 * 34; k += 256) {
    int ci = k / 340;
    int rem = k % 340;
    int lr = rem / 34, lc = rem % 34;
    int gr = band * 8 - 1 + lr, gc = lc - 1;
    float v = 0.f;
    if (gr >= 0 && gr < 32 && gc >= 0 && gc < 32) v = inb[(ci * 32 + gr) * 32 + gc];
    tile[k] = v;
  }
  __syncthreads();
  float acc[8][4];
#pragma unroll
  for (int oi = 0; oi < 8; ++oi) {
    float b = bsrc[og * 8 + oi];
#pragma unroll
    for (int p = 0; p < 4; ++p) acc[oi][p] = b;
  }
#pragma unroll
  for (int ci = 0; ci < 3; ++ci) {
    float iv[3][6];
#pragma unroll
    for (int ky = 0; ky < 3; ++ky)
#pragma unroll
      for (int dx = 0; dx < 6; ++dx)
        iv[ky][dx] = tile[ci * 340 + (r + ky) * 34 + c0 + dx];
#pragma unroll
    for (int oi = 0; oi < 8; ++oi) {
      const float* w9 = &wl[((size_t)ci * 32 + og * 8 + oi) * 9];
#pragma unroll
      for (int ky = 0; ky < 3; ++ky)
#pragma unroll
        for (int kx = 0; kx < 3; ++kx) {
          float wv = w9[ky * 3 + kx];
#pragma unroll
          for (int p = 0; p < 4; ++p) acc[oi][p] += wv * iv[ky][p + kx];
        }
    }
  }
#pragma unroll
  for (int oi = 0; oi < 8; ++oi)
#pragma unroll
    for (int p = 0; p < 4; ++p)
      ostg[(r * 32 + c0 + p) * 32 + og * 8 + oi] = f2bf(acc[oi][p]);
  __syncthreads();
  for (int u = t; u < 1024; u += 256) {
    int px = u >> 2, c8 = (u & 3) * 8;
    int4 v = *(const int4*)&ostg[px * 32 + c8];
    size_t gi = ((size_t)slot * 1024 + band * 256 + px) * 32 + c8;
    *(int4*)&hbuf[gi] = v;
  }
}

// ---------------- body conv32 helper: swizzled LDS, PRECOMPUTED addresses ----------------
template <int EPI>
static __device__ __forceinline__ void conv32_lds8(
    const unsigned short* __restrict__ srcP, unsigned short* __restrict__ dstP,
    const unsigned short* __restrict__ hb,
    const unsigned short* __restrict__ wtc, const float* __restrict__ bsrc,
    const int (&rdA)[6][3], const int (&wrA)[4][2],
    int w, int l, int col, int s4) {
  bf16x8 Bf[9][2];
  f32x4 bias4[2];
#pragma unroll
  for (int n = 0; n < 2; ++n) {
    bias4[n] = *(const f32x4*)&bsrc[n * 16 + s4 * 4];
#pragma unroll
    for (int tap = 0; tap < 9; ++tap)
      Bf[tap][n] = *(const bf16x8*)&wtc[((tap * 32) + n * 16 + col) * 32 + s4 * 8];
  }
  int rbase = w * 4;
#pragma unroll
  for (int xh = 0; xh < 2; ++xh) {
    bf16x8 Af[6][3];
#pragma unroll
    for (int rr = 0; rr < 6; ++rr)
#pragma unroll
      for (int kx = 0; kx < 3; ++kx)
        Af[rr][kx] = *(const bf16x8*)&srcP[rdA[rr][kx] + xh * 512];
    f32x4 acc[4][2];
#pragma unroll
    for (int m = 0; m < 4; ++m)
#pragma unroll
      for (int n = 0; n < 2; ++n) acc[m][n] = bias4[n];
    __builtin_amdgcn_s_setprio(1);
#pragma unroll
    for (int ky = 0; ky < 3; ++ky)
#pragma unroll
      for (int kx = 0; kx < 3; ++kx)
#pragma unroll
        for (int r = 0; r < 4; ++r)
#pragma unroll
          for (int n = 0; n < 2; ++n)
            acc[r][n] = mfma16(Bf[ky * 3 + kx][n], Af[r + ky][kx], acc[r][n]);
    __builtin_amdgcn_s_setprio(0);
#pragma unroll
    for (int r = 0; r < 4; ++r) {
      int row = rbase + r;
      int x = xh * 16 + col;
#pragma unroll
      for (int n = 0; n < 2; ++n) {
        unsigned li = (unsigned)(wrA[r][n] + xh * 512);
        float v0 = acc[r][n][0], v1 = acc[r][n][1], v2 = acc[r][n][2], v3 = acc[r][n][3];
        if (EPI == 0) {
          v0 = relu_f(v0); v1 = relu_f(v1); v2 = relu_f(v2); v3 = relu_f(v3);
        } else if (EPI == 1) {
          uint2 old = *(const uint2*)&dstP[li];
          v0 = bf2f((unsigned short)(old.x & 0xffff)) + 0.1f * v0;
          v1 = bf2f((unsigned short)(old.x >> 16)) + 0.1f * v1;
          v2 = bf2f((unsigned short)(old.y & 0xffff)) + 0.1f * v2;
          v3 = bf2f((unsigned short)(old.y >> 16)) + 0.1f * v3;
        } else if (EPI == 2) {
          uint2 hv = *(const uint2*)&hb[((unsigned)(row * 32 + x)) * 32 + n * 16 + s4 * 4];
          v0 += bf2f((unsigned short)(hv.x & 0xffff));
          v1 += bf2f((unsigned short)(hv.x >> 16));
          v2 += bf2f((unsigned short)(hv.y & 0xffff));
          v3 += bf2f((unsigned short)(hv.y >> 16));
        }
        uint2 o;
        o.x = (unsigned)f2bf(v0) | ((unsigned)f2bf(v1) << 16);
        o.y = (unsigned)f2bf(v2) | ((unsigned)f2bf(v3) << 16);
        *(uint2*)&dstP[li] = o;
      }
    }
  }
}

// ---------------- body mega-kernel: 4 ResBlocks + end(+h) + up1, all in LDS ----------------
__global__ __launch_bounds__(512, 1) void k_body(
    const unsigned short* __restrict__ hbuf, unsigned short* __restrict__ u1,
    const unsigned short* __restrict__ wt,
    const float* __restrict__ rb_b1, const float* __restrict__ rb_b2,
    const float* __restrict__ end_b, const float* __restrict__ up_b1,
    const int* __restrict__ slot_img) {
  int slot = blockIdx.x;
  int img = slot_img[slot];
  if (img < 0) return;
  int e = slot / CAP;
  int t = threadIdx.x;
  int w = t >> 6, l = t & 63;
  int col = l & 15, s4 = l >> 4;

  __shared__ __align__(16) unsigned short resP[34 * 34 * 32];
  __shared__ __align__(16) unsigned short tP[34 * 34 * 32];
  __shared__ __align__(16) unsigned short scr[8 * 512];

  int rdA[6][3];
  int wrA[4][2];
#pragma unroll
  for (int rr = 0; rr < 6; ++rr)
#pragma unroll
    for (int kx = 0; kx < 3; ++kx)
      rdA[rr][kx] = (int)swz((unsigned)((w * 4 + rr) * 34 + col + kx), (unsigned)s4);
#pragma unroll
  for (int r = 0; r < 4; ++r)
#pragma unroll
    for (int n = 0; n < 2; ++n)
      wrA[r][n] = (int)(swz((unsigned)((w * 4 + r + 1) * 34 + col + 1),
                            (unsigned)(n * 2 + (s4 >> 1))) + (s4 & 1) * 4);

  int4 z = make_int4(0, 0, 0, 0);
  for (int u = t; u < 4624; u += 512) {
    *(int4*)&resP[u * 8] = z;
    *(int4*)&tP[u * 8] = z;
  }
  __syncthreads();
  const unsigned short* hsl = hbuf + (size_t)slot * 32768;
  for (int u = t; u < 4096; u += 512) {
    int px = u >> 2, sl = u & 3;
    unsigned p = (unsigned)(((px >> 5) + 1) * 34 + (px & 31) + 1);
    *(int4*)&resP[swz(p, sl)] = *(const int4*)&hsl[px * 32 + sl * 8];
  }
  __syncthreads();

  unsigned short* wscr = &scr[w * 512];
  const unsigned short* wte = wt + (size_t)e * PER_E;

  for (int i = 0; i < NBLK; ++i) {
    conv32_lds8<0>(resP, tP, nullptr, wte + OFF_RB1 + i * 9216,
                   rb_b1 + (size_t)e * NBLK * 32 + i * 32, rdA, wrA, w, l, col, s4);
    __syncthreads();
    conv32_lds8<1>(tP, resP, nullptr, wte + OFF_RB2 + i * 9216,
                   rb_b2 + (size_t)e * NBLK * 32 + i * 32, rdA, wrA, w, l, col, s4);
    __syncthreads();
  }
  conv32_lds8<2>(resP, tP, hsl, wte + OFF_END, end_b + (size_t)e * 32, rdA, wrA,
                 w, l, col, s4);
  __syncthreads();

  // up1: conv 32->128 + pixel shuffle -> u1 [slot][64][64][32]
  {
    int og = w >> 1, rh = w & 1;
    const unsigned short* wtc = wte + OFF_UP1;
    const float* bsrc = up_b1 + (size_t)e * 128;
    bf16x8 Bf[9][2];
    float bias[2];
#pragma unroll
    for (int n = 0; n < 2; ++n) {
      int och = og * 32 + n * 16 + col;
      bias[n] = bsrc[och];
#pragma unroll
      for (int tap = 0; tap < 9; ++tap)
        Bf[tap][n] = *(const bf16x8*)&wtc[((tap * 128) + och) * 32 + s4 * 8];
    }
    unsigned short* u1g = u1 + (size_t)slot * 64 * 64 * 32;
#pragma unroll
    for (int xh = 0; xh < 2; ++xh) {
      int x0 = xh * 16;
#pragma unroll
      for (int rg = 0; rg < 4; ++rg) {
        int rbase = rh * 16 + rg * 4;
        bf16x8 Af[6][3];
#pragma unroll
        for (int rr = 0; rr < 6; ++rr)
#pragma unroll
          for (int kx = 0; kx < 3; ++kx)
            Af[rr][kx] = *(const bf16x8*)&tP[swz((rbase + rr) * 34 + x0 + col + kx, s4)];
        f32x4 acc[4][2];
#pragma unroll
        for (int m = 0; m < 4; ++m)
#pragma unroll
          for (int n = 0; n < 2; ++n) acc[m][n] = (f32x4){bias[n], bias[n], bias[n], bias[n]};
        __builtin_amdgcn_s_setprio(1);
#pragma unroll
        for (int ky = 0; ky < 3; ++ky)
#pragma unroll
          for (int kx = 0; kx < 3; ++kx)
#pragma unroll
            for (int r = 0; r < 4; ++r)
#pragma unroll
              for (int n = 0; n < 2; ++n)
                acc[r][n] = mfma16(Af[r + ky][kx], Bf[ky * 3 + kx][n], acc[r][n]);
        __builtin_amdgcn_s_setprio(0);
#pragma unroll
        for (int r = 0; r < 4; ++r) {
          int row = rbase + r;
#pragma unroll
          for (int n = 0; n < 2; ++n) {
            int och = og * 32 + n * 16 + col;
            int ryrx = och & 3, ccl = (och >> 2) & 7;
#pragma unroll
            for (int reg = 0; reg < 4; ++reg)
              wscr[(ryrx * 16 + s4 * 4 + reg) * 8 + ccl] = f2bf(acc[r][n][reg]);
          }
          int ryrx2 = l >> 4, px2 = l & 15;
          int4 yv = *(const int4*)&wscr[(ryrx2 * 16 + px2) * 8];
          int ry = ryrx2 >> 1, rx = ryrx2 & 1;
          int oy = 2 * row + ry, ox = 2 * (x0 + px2) + rx;
          *(int4*)&u1g[((size_t)oy * 64 + ox) * 32 + og * 8] = yv;
        }
      }
    }
  }
}

// ---------------- fused up2 + tail v3: all LDS addresses precomputed ----------------
__global__ __launch_bounds__(256) void k_uptail(
    const unsigned short* __restrict__ u1, float* __restrict__ out,
    const unsigned short* __restrict__ wt, const float* __restrict__ up_b2,
    const float* __restrict__ tail_b, const int* __restrict__ slot_img) {
  int slot = blockIdx.y;
  int img = slot_img[slot];
  if (img < 0) return;
  int e = slot / CAP;
  int b = blockIdx.x & 15;
  int xh2 = blockIdx.x >> 4;
  int t = threadIdx.x;
  int w = t >> 6, l = t & 63;
  int col = l & 15, s4 = l >> 4;

  __shared__ __align__(16) unsigned short u1t[8 * 36 * 32];
  __shared__ __align__(16) unsigned short u2t[10 * 66 * 32];

  // ---- precomputed addresses (swz shift-invariance: (Dp>>1)%4==0) ----
  int rdU[2][3];
#pragma unroll
  for (int rp = 0; rp < 2; ++rp)
#pragma unroll
    for (int kx = 0; kx < 3; ++kx)
      rdU[rp][kx] = (int)swz((unsigned)(rp * 36 + col + kx), (unsigned)s4);
  int stB[2][2][4];
#pragma unroll
  for (int yp = 0; yp < 2; ++yp)
#pragma unroll
    for (int n = 0; n < 2; ++n)
#pragma unroll
      for (int reg = 0; reg < 4; ++reg) {
        int ry = reg >> 1, rx = reg & 1;
        int pb = (2 * yp + ry - 1) * 66 + 2 * col + rx - 1;
        stB[yp][n][reg] = swzI(pb, w) + n * 4 + s4;
      }
  int rdT[4][3];
#pragma unroll
  for (int rr = 0; rr < 4; ++rr)
#pragma unroll
    for (int kx = 0; kx < 3; ++kx)
      rdT[rr][kx] = (int)swz((unsigned)((w * 2 + rr) * 66 + col + kx), (unsigned)s4);

  // stage u1 tile: rows 4b-2..4b+5, cols 32*xh2-2..+33
  const unsigned short* u1s = u1 + (size_t)slot * 64 * 64 * 32;
  int r0 = 4 * b - 2, c0g = 32 * xh2 - 2;
  for (int u = t; u < 8 * 36 * 4; u += 256) {
    int rr = u / 144;
    int rem = u - rr * 144;
    int cc = rem >> 2, sl = rem & 3;
    int gy = r0 + rr, gx = c0g + cc;
    int4 v = make_int4(0, 0, 0, 0);
    if (gy >= 0 && gy < 64 && gx >= 0 && gx < 64)
      v = *(const int4*)&u1s[((size_t)gy * 64 + gx) * 32 + sl * 8];
    *(int4*)&u1t[swz((unsigned)(rr * 36 + cc), sl)] = v;
  }

  // up2 weights + bias (swapped form)
  const unsigned short* wtc = wt + (size_t)e * PER_E + OFF_UP2;
  bf16x8 Bf[9][2];
  f32x4 bias4[2];
#pragma unroll
  for (int n = 0; n < 2; ++n) {
    bias4[n] = *(const f32x4*)&up_b2[(size_t)e * 128 + w * 32 + n * 16 + s4 * 4];
#pragma unroll
    for (int tap = 0; tap < 9; ++tap)
      Bf[tap][n] = *(const bf16x8*)&wtc[((tap * 128) + w * 32 + n * 16 + col) * 32 + s4 * 8];
  }
  // tail weights
  const unsigned short* wtt = wt + (size_t)e * PER_E + OFF_TAIL;
  bf16x8 Bt[9];
  float biast = 0.f;
  if (col < 3) biast = tail_b[e * 3 + col];
#pragma unroll
  for (int tap = 0; tap < 9; ++tap) {
    if (col < 3)
      Bt[tap] = *(const bf16x8*)&wtt[((tap * 3) + col) * 32 + s4 * 8];
    else {
      bf16x8 bb;
#pragma unroll
      for (int j = 0; j < 8; ++j) bb[j] = (short)0;
      Bt[tap] = bb;
    }
  }
  __syncthreads();

  // up2: xg outer, yy inner with rolling 3-row Af window
#pragma unroll
  for (int xg = 0; xg < 3; ++xg) {
    bf16x8 Af[3][3];
#pragma unroll
    for (int rr = 0; rr < 3; ++rr)
#pragma unroll
      for (int kx = 0; kx < 3; ++kx)
        Af[rr][kx] = *(const bf16x8*)&u1t[rdU[rr & 1][kx] + (rr >> 1) * 2304 + xg * 512];
#pragma unroll
    for (int yy = 0; yy < 6; ++yy) {
      if (yy > 0) {
        int row = yy + 2;
#pragma unroll
        for (int kx = 0; kx < 3; ++kx)
          Af[(yy + 2) % 3][kx] =
              *(const bf16x8*)&u1t[rdU[row & 1][kx] + (row >> 1) * 2304 + xg * 512];
      }
      f32x4 acc[2];
#pragma unroll
      for (int n = 0; n < 2; ++n) acc[n] = bias4[n];
      __builtin_amdgcn_s_setprio(1);
#pragma unroll
      for (int ky = 0; ky < 3; ++ky)
#pragma unroll
        for (int kx = 0; kx < 3; ++kx)
#pragma unroll
          for (int n = 0; n < 2; ++n)
            acc[n] = mfma16(Bf[ky * 3 + kx][n], Af[(yy + ky) % 3][kx], acc[n]);
      __builtin_amdgcn_s_setprio(0);
#pragma unroll
      for (int n = 0; n < 2; ++n)
#pragma unroll
        for (int reg = 0; reg < 4; ++reg) {
          int ry = reg >> 1, rx = reg & 1;
          if ((yy == 0 && ry == 0) || (yy == 5 && ry == 1)) continue;  // oyl out of tile
          bool valid = (xg == 1) || (xg == 0 && (col > 0 || rx == 1)) ||
                       (xg == 2 && (2 * col + rx <= 2));
          float v = acc[n][reg];
          if (b == 0 && yy == 0 && ry == 1) v = 0.f;                        // gy2 == -1
          if (b == 15 && yy == 5 && ry == 0) v = 0.f;                       // gy2 == 128
          if (xh2 == 0 && xg == 0 && col == 0 && rx == 1) v = 0.f;          // gx2 == -1
          if (xh2 == 1 && xg == 2 && col == 1 && rx == 0) v = 0.f;          // gx2 == 128
          if (valid)
            u2t[(unsigned)(stB[yy & 1][n][reg] + (yy >> 1) * 8448 + xg * 1024)] = f2bf(v);
        }
    }
  }
  __syncthreads();

  // tail: out rows 8b..8b+7, wave w does rows w*2, w*2+1; cols 64*xh2..+63
#pragma unroll
  for (int gx = 0; gx < 4; ++gx) {
    bf16x8 At[4][3];
#pragma unroll
    for (int rr = 0; rr < 4; ++rr)
#pragma unroll
      for (int kx = 0; kx < 3; ++kx)
        At[rr][kx] = *(const bf16x8*)&u2t[rdT[rr][kx] + gx * 512];
    f32x4 acc[2];
#pragma unroll
    for (int r = 0; r < 2; ++r) acc[r] = (f32x4){biast, biast, biast, biast};
    __builtin_amdgcn_s_setprio(1);
#pragma unroll
    for (int ky = 0; ky < 3; ++ky)
#pragma unroll
      for (int kx = 0; kx < 3; ++kx)
#pragma unroll
        for (int r = 0; r < 2; ++r)
          acc[r] = mfma16(At[r + ky][kx], Bt[ky * 3 + kx], acc[r]);
    __builtin_amdgcn_s_setprio(0);
    if (col < 3) {
#pragma unroll
      for (int r = 0; r < 2; ++r) {
        int grow = 8 * b + w * 2 + r;
        int gcol = 64 * xh2 + gx * 16 + s4 * 4;
        *(float4*)&out[(((size_t)img * 3 + col) * 128 + grow) * 128 + gcol] =
            make_float4(acc[r][0], acc[r][1], acc[r][2], acc[r][3]);
      }
    }
  }
}

extern "C" void kernel_launch(void* const* d_in, const int* in_sizes, int n_in,
                              void* d_out, int out_size, void* d_ws, size_t ws_size,
                              hipStream_t stream) {
  const float* inputs = (const float*)d_in[0];
  const float* cls_w = (const float*)d_in[1];
  const float* cls_b = (const float*)d_in[2];
  const float* cls_fw = (const float*)d_in[3];
  const float* cls_fb = (const float*)d_in[4];
  const float* head_w = (const float*)d_in[5];
  const float* head_b = (const float*)d_in[6];
  const float* rb_w1 = (const float*)d_in[7];
  const float* rb_b1 = (const float*)d_in[8];
  const float* rb_w2 = (const float*)d_in[9];
  const float* rb_b2 = (const float*)d_in[10];
  const float* end_w = (const float*)d_in[11];
  const float* end_b = (const float*)d_in[12];
  const float* up_w1 = (const float*)d_in[13];
  const float* up_b1 = (const float*)d_in[14];
  const float* up_w2 = (const float*)d_in[15];
  const float* up_b2 = (const float*)d_in[16];
  const float* tail_w = (const float*)d_in[17];
  const float* tail_b = (const float*)d_in[18];
  float* out = (float*)d_out;
  char* ws = (char*)d_ws;

  int N = in_sizes[0] / 3072;  // 128

  int* slot_img = (int*)(ws + 512);
  float* part = (float*)(ws + 4096);                     // [N][4][32]
  unsigned short* wt = (unsigned short*)(ws + 131072);   // 1.26 MB transformed weights
  const size_t ABUF = (size_t)NSLOT * 1024 * 32 * 2;     // 12,582,912
  size_t o_h = 1572864;
  unsigned short* h = (unsigned short*)(ws + o_h);
  unsigned short* u1 = (unsigned short*)(ws + o_h + ABUF);

  k_zero<<<2048, 256, 0, stream>>>((float4*)out, out_size / 4);
  k_cls_conv<<<dim3(4, N), 256, 0, stream>>>(inputs, cls_w, cls_b, part);
  k_score_route<<<1, 256, 0, stream>>>(part, cls_fw, cls_fb, slot_img, N);

  k_head<<<dim3(4, NSLOT), 256, 0, stream>>>(inputs, h, head_w, head_b, slot_img,
                                             rb_w1, rb_w2, end_w, up_w1, up_w2, tail_w, wt);

  k_body<<<NSLOT, 512, 0, stream>>>(h, u1, wt, rb_b1, rb_b2, end_b, up_b1, slot_img);

  k_uptail<<<dim3(32, NSLOT), 256, 0, stream>>>(u1, out, wt, up_b2, tail_b, slot_img);
}

// Round 15
// 170.268 us; speedup vs baseline: 1.5488x; 1.0055x over previous
//
#include <hip/hip_runtime.h>

#define EXPN 4
#define CAP 48
#define NSLOT 192   // EXPN*CAP
#define NBLK 4

// transformed-weight layout (bf16), per expert:
#define OFF_RB1 0         // + i*9216
#define OFF_RB2 36864     // + i*9216
#define OFF_END 73728
#define OFF_UP1 82944
#define OFF_UP2 119808
#define OFF_TAIL 156672
#define PER_E 157536

typedef __attribute__((ext_vector_type(8))) short bf16x8;
typedef __attribute__((ext_vector_type(4))) float f32x4;

static __device__ __forceinline__ float bf2f(unsigned short s) {
  union { unsigned u; float f; } c; c.u = ((unsigned)s) << 16; return c.f;
}
static __device__ __forceinline__ unsigned short f2bf(float f) {
  union { float f; unsigned u; } c; c.f = f;
  unsigned u = c.u;
  return (unsigned short)((u + 0x7fffu + ((u >> 16) & 1u)) >> 16);  // RNE
}
static __device__ __forceinline__ f32x4 mfma16(bf16x8 a, bf16x8 b, f32x4 c) {
  return __builtin_amdgcn_mfma_f32_16x16x32_bf16(a, b, c, 0, 0, 0);
}
static __device__ __forceinline__ float relu_f(float x) { return fmaxf(x, 0.f); }

// LDS channel-last swizzle: pixel p, 16B-slot s (0..3) -> shorts offset.
// Shift-invariance: (Dp>>1)%4==0  =>  swz(p+Dp,s) == swz(p,s) + Dp*32.
static __device__ __forceinline__ unsigned swz(unsigned p, unsigned s) {
  return p * 32 + ((s ^ ((p >> 1) & 3u)) * 8);
}
static __device__ __forceinline__ int swzI(int p, int s) {
  return p * 32 + ((s ^ ((p >> 1) & 3)) * 8);
}

// ---------------- classifier stage A + zero-out prologue + wxform prologue ----------------
// 512 blocks x 256 thr. Grid-stride prologues hide the 25MB zero + weight transform
// under the (mostly idle) classifier conv (r14: zero+wxform cost ~9us of launches).
__global__ __launch_bounds__(256) void k_cls_conv(
    const float* __restrict__ x, const float* __restrict__ cw,
    const float* __restrict__ cb, float* __restrict__ part,
    float4* __restrict__ outz, int n4,
    const float* __restrict__ rb_w1, const float* __restrict__ rb_w2,
    const float* __restrict__ end_w, const float* __restrict__ up_w1,
    const float* __restrict__ up_w2, const float* __restrict__ tail_w,
    unsigned short* __restrict__ wt) {
  int n = blockIdx.y, band = blockIdx.x, t = threadIdx.x;
  int bid = blockIdx.y * 4 + blockIdx.x;  // 0..511
  // zero d_out (overflowed images must stay zero)
  {
    float4 z = make_float4(0.f, 0.f, 0.f, 0.f);
    for (int i = bid * 256 + t; i < n4; i += 512 * 256) outz[i] = z;
  }
  // weight transform fp32 [och][ich][3][3] -> bf16 [tap][och][ich]
  for (int idx = bid * 256 + t; idx < EXPN * PER_E; idx += 512 * 256) {
    int e = idx / PER_E, r = idx % PER_E;
    const float* src;
    int c, OC;
    if (r < OFF_RB2) {
      int i = r / 9216; c = r % 9216; OC = 32;
      src = rb_w1 + ((size_t)e * NBLK + i) * 9216;
    } else if (r < OFF_END) {
      int i = (r - OFF_RB2) / 9216; c = (r - OFF_RB2) % 9216; OC = 32;
      src = rb_w2 + ((size_t)e * NBLK + i) * 9216;
    } else if (r < OFF_UP1) {
      c = r - OFF_END; OC = 32;
      src = end_w + (size_t)e * 9216;
    } else if (r < OFF_UP2) {
      c = r - OFF_UP1; OC = 128;
      src = up_w1 + (size_t)e * 36864;
    } else if (r < OFF_TAIL) {
      c = r - OFF_UP2; OC = 128;
      src = up_w2 + (size_t)e * 36864;
    } else {
      c = r - OFF_TAIL; OC = 3;
      src = tail_w + (size_t)e * 864;
    }
    int tap = c / (OC * 32);
    int rem = c % (OC * 32);
    int och = rem / 32, ich = rem % 32;
    wt[idx] = f2bf(src[(och * 32 + ich) * 9 + tap]);
  }
  // classifier conv
  int og = t >> 6, r = (t >> 3) & 7, cg = t & 7;
  int c0 = cg * 4;
  __shared__ float wl[3 * 32 * 9];
  __shared__ float tile[3 * 10 * 34];
  for (int k = t; k < 864; k += 256) {
    int o = k / 27;
    int rem = k % 27;
    int ci = rem / 9, tap = rem % 9;
    wl[(ci * 32 + o) * 9 + tap] = cw[k];
  }
  const float* inb = x + (size_t)n * 3072;
  for (int k = t; k < 1020; k += 256) {
    int ci = k / 340;
    int rem = k % 340;
    int lr = rem / 34, lc = rem % 34;
    int gr = band * 8 - 1 + lr, gc = lc - 1;
    float v = 0.f;
    if (gr >= 0 && gr < 32 && gc >= 0 && gc < 32) v = inb[(ci * 32 + gr) * 32 + gc];
    tile[k] = v;
  }
  __syncthreads();
  float acc[8][4];
#pragma unroll
  for (int oi = 0; oi < 8; ++oi) {
    float b = cb[og * 8 + oi];
#pragma unroll
    for (int p = 0; p < 4; ++p) acc[oi][p] = b;
  }
#pragma unroll
  for (int ci = 0; ci < 3; ++ci) {
    float iv[3][6];
#pragma unroll
    for (int ky = 0; ky < 3; ++ky)
#pragma unroll
      for (int dx = 0; dx < 6; ++dx)
        iv[ky][dx] = tile[ci * 340 + (r + ky) * 34 + c0 + dx];
#pragma unroll
    for (int oi = 0; oi < 8; ++oi) {
      const float* w9 = &wl[((size_t)ci * 32 + og * 8 + oi) * 9];
#pragma unroll
      for (int ky = 0; ky < 3; ++ky)
#pragma unroll
        for (int kx = 0; kx < 3; ++kx) {
          float wv = w9[ky * 3 + kx];
#pragma unroll
          for (int p = 0; p < 4; ++p) acc[oi][p] += wv * iv[ky][p + kx];
        }
    }
  }
#pragma unroll
  for (int oi = 0; oi < 8; ++oi) {
    float s = relu_f(acc[oi][0]) + relu_f(acc[oi][1]) + relu_f(acc[oi][2]) + relu_f(acc[oi][3]);
#pragma unroll
    for (int off = 32; off >= 1; off >>= 1) s += __shfl_down(s, off, 64);
    if ((t & 63) == 0) part[((size_t)n * 4 + band) * 32 + og * 8 + oi] = s;
  }
}

// ---------------- score + route (fused, 1 block) ----------------
__global__ __launch_bounds__(256) void k_score_route(
    const float* __restrict__ part, const float* __restrict__ fw,
    const float* __restrict__ fb, int* __restrict__ slot_img, int N) {
  __shared__ int assign_s[256];
  int t = threadIdx.x;
  for (int n = t; n < N; n += 256) {
    float cm[32];
#pragma unroll
    for (int o = 0; o < 32; ++o) {
      float s = part[((size_t)n * 4 + 0) * 32 + o] + part[((size_t)n * 4 + 1) * 32 + o] +
                part[((size_t)n * 4 + 2) * 32 + o] + part[((size_t)n * 4 + 3) * 32 + o];
      cm[o] = s * (1.f / 1024.f);
    }
    float best = -1e30f;
    int bi = 0;
    for (int e = 0; e < EXPN; ++e) {
      float sc = fb[e];
#pragma unroll
      for (int o = 0; o < 32; ++o) sc += cm[o] * fw[e * 32 + o];
      if (sc > best) { best = sc; bi = e; }
    }
    assign_s[n] = bi;
  }
  __syncthreads();
  if (t == 0) {
    int cnt[EXPN];
    for (int e = 0; e < EXPN; ++e) cnt[e] = 0;
    for (int k = 0; k < NSLOT; ++k) slot_img[k] = -1;
    for (int n = 0; n < N; ++n) {
      int e = assign_s[n];
      if (cnt[e] < CAP) { slot_img[e * CAP + cnt[e]] = n; cnt[e]++; }
    }
  }
}

// ---------------- head: conv 3->32 fp32 VALU -> h (bf16 ch-last) ----------------
__global__ __launch_bounds__(256) void k_head(
    const float* __restrict__ x, unsigned short* __restrict__ hbuf,
    const float* __restrict__ wglob, const float* __restrict__ bglob,
    const int* __restrict__ slot_img) {
  int slot = blockIdx.y;
  int band = blockIdx.x;
  int t = threadIdx.x;
  int img = slot_img[slot];
  if (img < 0) return;
  int e = slot / CAP;
  int og = t >> 6, r = (t >> 3) & 7, cg = t & 7;
  int c0 = cg * 4;
  __shared__ float wl[3 * 32 * 9];
  __shared__ float tile[3 * 10 * 34];
  __shared__ __align__(16) unsigned short ostg[256 * 32];
  const float* wsrc = wglob + (size_t)e * 32 * 27;
  for (int k = t; k < 864; k += 256) {
    int o = k / 27;
    int rem = k % 27;
    int ci = rem / 9, tap = rem % 9;
    wl[(ci * 32 + o) * 9 + tap] = wsrc[k];
  }
  const float* bsrc = bglob + (size_t)e * 32;
  const float* inb = x + (size_t)img * 3072;
  for (int k = t; k < 3 * 10 * 34; k += 256) {
    int ci = k / 340;
    int rem = k % 340;
    int lr = rem / 34, lc = rem % 34;
    int gr = band * 8 - 1 + lr, gc = lc - 1;
    float v = 0.f;
    if (gr >= 0 && gr < 32 && gc >= 0 && gc < 32) v = inb[(ci * 32 + gr) * 32 + gc];
    tile[k] = v;
  }
  __syncthreads();
  float acc[8][4];
#pragma unroll
  for (int oi = 0; oi < 8; ++oi) {
    float b = bsrc[og * 8 + oi];
#pragma unroll
    for (int p = 0; p < 4; ++p) acc[oi][p] = b;
  }
#pragma unroll
  for (int ci = 0; ci < 3; ++ci) {
    float iv[3][6];
#pragma unroll
    for (int ky = 0; ky < 3; ++ky)
#pragma unroll
      for (int dx = 0; dx < 6; ++dx)
        iv[ky][dx] = tile[ci * 340 + (r + ky) * 34 + c0 + dx];
#pragma unroll
    for (int oi = 0; oi < 8; ++oi) {
      const float* w9 = &wl[((size_t)ci * 32 + og * 8 + oi) * 9];
#pragma unroll
      for (int ky = 0; ky < 3; ++ky)
#pragma unroll
        for (int kx = 0; kx < 3; ++kx) {
          float wv = w9[ky * 3 + kx];
#pragma unroll
          for (int p = 0; p < 4; ++p) acc[oi][p] += wv * iv[ky][p + kx];
        }
    }
  }
#pragma unroll
  for (int oi = 0; oi < 8; ++oi)
#pragma unroll
    for (int p = 0; p < 4; ++p)
      ostg[(r * 32 + c0 + p) * 32 + og * 8 + oi] = f2bf(acc[oi][p]);
  __syncthreads();
  for (int u = t; u < 1024; u += 256) {
    int px = u >> 2, c8 = (u & 3) * 8;
    int4 v = *(const int4*)&ostg[px * 32 + c8];
    size_t gi = ((size_t)slot * 1024 + band * 256 + px) * 32 + c8;
    *(int4*)&hbuf[gi] = v;
  }
}

// ---------------- body conv32 helper: swizzled LDS, PRECOMPUTED addresses ----------------
template <int EPI>
static __device__ __forceinline__ void conv32_lds8(
    const unsigned short* __restrict__ srcP, unsigned short* __restrict__ dstP,
    const unsigned short* __restrict__ hb,
    const unsigned short* __restrict__ wtc, const float* __restrict__ bsrc,
    const int (&rdA)[6][3], const int (&wrA)[4][2],
    int w, int l, int col, int s4) {
  bf16x8 Bf[9][2];
  f32x4 bias4[2];
#pragma unroll
  for (int n = 0; n < 2; ++n) {
    bias4[n] = *(const f32x4*)&bsrc[n * 16 + s4 * 4];
#pragma unroll
    for (int tap = 0; tap < 9; ++tap)
      Bf[tap][n] = *(const bf16x8*)&wtc[((tap * 32) + n * 16 + col) * 32 + s4 * 8];
  }
  int rbase = w * 4;
#pragma unroll
  for (int xh = 0; xh < 2; ++xh) {
    bf16x8 Af[6][3];
#pragma unroll
    for (int rr = 0; rr < 6; ++rr)
#pragma unroll
      for (int kx = 0; kx < 3; ++kx)
        Af[rr][kx] = *(const bf16x8*)&srcP[rdA[rr][kx] + xh * 512];
    f32x4 acc[4][2];
#pragma unroll
    for (int m = 0; m < 4; ++m)
#pragma unroll
      for (int n = 0; n < 2; ++n) acc[m][n] = bias4[n];
    __builtin_amdgcn_s_setprio(1);
#pragma unroll
    for (int ky = 0; ky < 3; ++ky)
#pragma unroll
      for (int kx = 0; kx < 3; ++kx)
#pragma unroll
        for (int r = 0; r < 4; ++r)
#pragma unroll
          for (int n = 0; n < 2; ++n)
            acc[r][n] = mfma16(Bf[ky * 3 + kx][n], Af[r + ky][kx], acc[r][n]);
    __builtin_amdgcn_s_setprio(0);
#pragma unroll
    for (int r = 0; r < 4; ++r) {
      int row = rbase + r;
      int x = xh * 16 + col;
#pragma unroll
      for (int n = 0; n < 2; ++n) {
        unsigned li = (unsigned)(wrA[r][n] + xh * 512);
        float v0 = acc[r][n][0], v1 = acc[r][n][1], v2 = acc[r][n][2], v3 = acc[r][n][3];
        if (EPI == 0) {
          v0 = relu_f(v0); v1 = relu_f(v1); v2 = relu_f(v2); v3 = relu_f(v3);
        } else if (EPI == 1) {
          uint2 old = *(const uint2*)&dstP[li];
          v0 = bf2f((unsigned short)(old.x & 0xffff)) + 0.1f * v0;
          v1 = bf2f((unsigned short)(old.x >> 16)) + 0.1f * v1;
          v2 = bf2f((unsigned short)(old.y & 0xffff)) + 0.1f * v2;
          v3 = bf2f((unsigned short)(old.y >> 16)) + 0.1f * v3;
        } else if (EPI == 2) {
          uint2 hv = *(const uint2*)&hb[((unsigned)(row * 32 + x)) * 32 + n * 16 + s4 * 4];
          v0 += bf2f((unsigned short)(hv.x & 0xffff));
          v1 += bf2f((unsigned short)(hv.x >> 16));
          v2 += bf2f((unsigned short)(hv.y & 0xffff));
          v3 += bf2f((unsigned short)(hv.y >> 16));
        }
        uint2 o;
        o.x = (unsigned)f2bf(v0) | ((unsigned)f2bf(v1) << 16);
        o.y = (unsigned)f2bf(v2) | ((unsigned)f2bf(v3) << 16);
        *(uint2*)&dstP[li] = o;
      }
    }
  }
}

// ---------------- body mega-kernel: 4 ResBlocks + end(+h) + up1, all in LDS ----------------
__global__ __launch_bounds__(512, 1) void k_body(
    const unsigned short* __restrict__ hbuf, unsigned short* __restrict__ u1,
    const unsigned short* __restrict__ wt,
    const float* __restrict__ rb_b1, const float* __restrict__ rb_b2,
    const float* __restrict__ end_b, const float* __restrict__ up_b1,
    const int* __restrict__ slot_img) {
  int slot = blockIdx.x;
  int img = slot_img[slot];
  if (img < 0) return;
  int e = slot / CAP;
  int t = threadIdx.x;
  int w = t >> 6, l = t & 63;
  int col = l & 15, s4 = l >> 4;

  __shared__ __align__(16) unsigned short resP[34 * 34 * 32];
  __shared__ __align__(16) unsigned short tP[34 * 34 * 32];
  __shared__ __align__(16) unsigned short scr[8 * 512];

  int rdA[6][3];
  int wrA[4][2];
#pragma unroll
  for (int rr = 0; rr < 6; ++rr)
#pragma unroll
    for (int kx = 0; kx < 3; ++kx)
      rdA[rr][kx] = (int)swz((unsigned)((w * 4 + rr) * 34 + col + kx), (unsigned)s4);
#pragma unroll
  for (int r = 0; r < 4; ++r)
#pragma unroll
    for (int n = 0; n < 2; ++n)
      wrA[r][n] = (int)(swz((unsigned)((w * 4 + r + 1) * 34 + col + 1),
                            (unsigned)(n * 2 + (s4 >> 1))) + (s4 & 1) * 4);

  int4 z = make_int4(0, 0, 0, 0);
  for (int u = t; u < 4624; u += 512) {
    *(int4*)&resP[u * 8] = z;
    *(int4*)&tP[u * 8] = z;
  }
  __syncthreads();
  const unsigned short* hsl = hbuf + (size_t)slot * 32768;
  for (int u = t; u < 4096; u += 512) {
    int px = u >> 2, sl = u & 3;
    unsigned p = (unsigned)(((px >> 5) + 1) * 34 + (px & 31) + 1);
    *(int4*)&resP[swz(p, sl)] = *(const int4*)&hsl[px * 32 + sl * 8];
  }
  __syncthreads();

  unsigned short* wscr = &scr[w * 512];
  const unsigned short* wte = wt + (size_t)e * PER_E;

  for (int i = 0; i < NBLK; ++i) {
    conv32_lds8<0>(resP, tP, nullptr, wte + OFF_RB1 + i * 9216,
                   rb_b1 + (size_t)e * NBLK * 32 + i * 32, rdA, wrA, w, l, col, s4);
    __syncthreads();
    conv32_lds8<1>(tP, resP, nullptr, wte + OFF_RB2 + i * 9216,
                   rb_b2 + (size_t)e * NBLK * 32 + i * 32, rdA, wrA, w, l, col, s4);
    __syncthreads();
  }
  conv32_lds8<2>(resP, tP, hsl, wte + OFF_END, end_b + (size_t)e * 32, rdA, wrA,
                 w, l, col, s4);
  __syncthreads();

  // up1: conv 32->128 + pixel shuffle -> u1 [slot][64][64][32]
  {
    int og = w >> 1, rh = w & 1;
    const unsigned short* wtc = wte + OFF_UP1;
    const float* bsrc = up_b1 + (size_t)e * 128;
    bf16x8 Bf[9][2];
    float bias[2];
#pragma unroll
    for (int n = 0; n < 2; ++n) {
      int och = og * 32 + n * 16 + col;
      bias[n] = bsrc[och];
#pragma unroll
      for (int tap = 0; tap < 9; ++tap)
        Bf[tap][n] = *(const bf16x8*)&wtc[((tap * 128) + och) * 32 + s4 * 8];
    }
    unsigned short* u1g = u1 + (size_t)slot * 64 * 64 * 32;
#pragma unroll
    for (int xh = 0; xh < 2; ++xh) {
      int x0 = xh * 16;
#pragma unroll
      for (int rg = 0; rg < 4; ++rg) {
        int rbase = rh * 16 + rg * 4;
        bf16x8 Af[6][3];
#pragma unroll
        for (int rr = 0; rr < 6; ++rr)
#pragma unroll
          for (int kx = 0; kx < 3; ++kx)
            Af[rr][kx] = *(const bf16x8*)&tP[swz((rbase + rr) * 34 + x0 + col + kx, s4)];
        f32x4 acc[4][2];
#pragma unroll
        for (int m = 0; m < 4; ++m)
#pragma unroll
          for (int n = 0; n < 2; ++n) acc[m][n] = (f32x4){bias[n], bias[n], bias[n], bias[n]};
        __builtin_amdgcn_s_setprio(1);
#pragma unroll
        for (int ky = 0; ky < 3; ++ky)
#pragma unroll
          for (int kx = 0; kx < 3; ++kx)
#pragma unroll
            for (int r = 0; r < 4; ++r)
#pragma unroll
              for (int n = 0; n < 2; ++n)
                acc[r][n] = mfma16(Af[r + ky][kx], Bf[ky * 3 + kx][n], acc[r][n]);
        __builtin_amdgcn_s_setprio(0);
#pragma unroll
        for (int r = 0; r < 4; ++r) {
          int row = rbase + r;
#pragma unroll
          for (int n = 0; n < 2; ++n) {
            int och = og * 32 + n * 16 + col;
            int ryrx = och & 3, ccl = (och >> 2) & 7;
#pragma unroll
            for (int reg = 0; reg < 4; ++reg)
              wscr[(ryrx * 16 + s4 * 4 + reg) * 8 + ccl] = f2bf(acc[r][n][reg]);
          }
          int ryrx2 = l >> 4, px2 = l & 15;
          int4 yv = *(const int4*)&wscr[(ryrx2 * 16 + px2) * 8];
          int ry = ryrx2 >> 1, rx = ryrx2 & 1;
          int oy = 2 * row + ry, ox = 2 * (x0 + px2) + rx;
          *(int4*)&u1g[((size_t)oy * 64 + ox) * 32 + og * 8] = yv;
        }
      }
    }
  }
}

// ---------------- fused up2 + tail v3: all LDS addresses precomputed ----------------
__global__ __launch_bounds__(256) void k_uptail(
    const unsigned short* __restrict__ u1, float* __restrict__ out,
    const unsigned short* __restrict__ wt, const float* __restrict__ up_b2,
    const float* __restrict__ tail_b, const int* __restrict__ slot_img) {
  int slot = blockIdx.y;
  int img = slot_img[slot];
  if (img < 0) return;
  int e = slot / CAP;
  int b = blockIdx.x & 15;
  int xh2 = blockIdx.x >> 4;
  int t = threadIdx.x;
  int w = t >> 6, l = t & 63;
  int col = l & 15, s4 = l >> 4;

  __shared__ __align__(16) unsigned short u1t[8 * 36 * 32];
  __shared__ __align__(16) unsigned short u2t[10 * 66 * 32];

  int rdU[2][3];
#pragma unroll
  for (int rp = 0; rp < 2; ++rp)
#pragma unroll
    for (int kx = 0; kx < 3; ++kx)
      rdU[rp][kx] = (int)swz((unsigned)(rp * 36 + col + kx), (unsigned)s4);
  int stB[2][2][4];
#pragma unroll
  for (int yp = 0; yp < 2; ++yp)
#pragma unroll
    for (int n = 0; n < 2; ++n)
#pragma unroll
      for (int reg = 0; reg < 4; ++reg) {
        int ry = reg >> 1, rx = reg & 1;
        int pb = (2 * yp + ry - 1) * 66 + 2 * col + rx - 1;
        stB[yp][n][reg] = swzI(pb, w) + n * 4 + s4;
      }
  int rdT[4][3];
#pragma unroll
  for (int rr = 0; rr < 4; ++rr)
#pragma unroll
    for (int kx = 0; kx < 3; ++kx)
      rdT[rr][kx] = (int)swz((unsigned)((w * 2 + rr) * 66 + col + kx), (unsigned)s4);

  const unsigned short* u1s = u1 + (size_t)slot * 64 * 64 * 32;
  int r0 = 4 * b - 2, c0g = 32 * xh2 - 2;
  for (int u = t; u < 8 * 36 * 4; u += 256) {
    int rr = u / 144;
    int rem = u - rr * 144;
    int cc = rem >> 2, sl = rem & 3;
    int gy = r0 + rr, gx = c0g + cc;
    int4 v = make_int4(0, 0, 0, 0);
    if (gy >= 0 && gy < 64 && gx >= 0 && gx < 64)
      v = *(const int4*)&u1s[((size_t)gy * 64 + gx) * 32 + sl * 8];
    *(int4*)&u1t[swz((unsigned)(rr * 36 + cc), sl)] = v;
  }

  const unsigned short* wtc = wt + (size_t)e * PER_E + OFF_UP2;
  bf16x8 Bf[9][2];
  f32x4 bias4[2];
#pragma unroll
  for (int n = 0; n < 2; ++n) {
    bias4[n] = *(const f32x4*)&up_b2[(size_t)e * 128 + w * 32 + n * 16 + s4 * 4];
#pragma unroll
    for (int tap = 0; tap < 9; ++tap)
      Bf[tap][n] = *(const bf16x8*)&wtc[((tap * 128) + w * 32 + n * 16 + col) * 32 + s4 * 8];
  }
  const unsigned short* wtt = wt + (size_t)e * PER_E + OFF_TAIL;
  bf16x8 Bt[9];
  float biast = 0.f;
  if (col < 3) biast = tail_b[e * 3 + col];
#pragma unroll
  for (int tap = 0; tap < 9; ++tap) {
    if (col < 3)
      Bt[tap] = *(const bf16x8*)&wtt[((tap * 3) + col) * 32 + s4 * 8];
    else {
      bf16x8 bb;
#pragma unroll
      for (int j = 0; j < 8; ++j) bb[j] = (short)0;
      Bt[tap] = bb;
    }
  }
  __syncthreads();

#pragma unroll
  for (int xg = 0; xg < 3; ++xg) {
    bf16x8 Af[3][3];
#pragma unroll
    for (int rr = 0; rr < 3; ++rr)
#pragma unroll
      for (int kx = 0; kx < 3; ++kx)
        Af[rr][kx] = *(const bf16x8*)&u1t[rdU[rr & 1][kx] + (rr >> 1) * 2304 + xg * 512];
#pragma unroll
    for (int yy = 0; yy < 6; ++yy) {
      if (yy > 0) {
        int row = yy + 2;
#pragma unroll
        for (int kx = 0; kx < 3; ++kx)
          Af[(yy + 2) % 3][kx] =
              *(const bf16x8*)&u1t[rdU[row & 1][kx] + (row >> 1) * 2304 + xg * 512];
      }
      f32x4 acc[2];
#pragma unroll
      for (int n = 0; n < 2; ++n) acc[n] = bias4[n];
      __builtin_amdgcn_s_setprio(1);
#pragma unroll
      for (int ky = 0; ky < 3; ++ky)
#pragma unroll
        for (int kx = 0; kx < 3; ++kx)
#pragma unroll
          for (int n = 0; n < 2; ++n)
            acc[n] = mfma16(Bf[ky * 3 + kx][n], Af[(yy + ky) % 3][kx], acc[n]);
      __builtin_amdgcn_s_setprio(0);
#pragma unroll
      for (int n = 0; n < 2; ++n)
#pragma unroll
        for (int reg = 0; reg < 4; ++reg) {
          int ry = reg >> 1, rx = reg & 1;
          if ((yy == 0 && ry == 0) || (yy == 5 && ry == 1)) continue;  // oyl out of tile
          bool valid = (xg == 1) || (xg == 0 && (col > 0 || rx == 1)) ||
                       (xg == 2 && (2 * col + rx <= 2));
          float v = acc[n][reg];
          if (b == 0 && yy == 0 && ry == 1) v = 0.f;                        // gy2 == -1
          if (b == 15 && yy == 5 && ry == 0) v = 0.f;                       // gy2 == 128
          if (xh2 == 0 && xg == 0 && col == 0 && rx == 1) v = 0.f;          // gx2 == -1
          if (xh2 == 1 && xg == 2 && col == 1 && rx == 0) v = 0.f;          // gx2 == 128
          if (valid)
            u2t[(unsigned)(stB[yy & 1][n][reg] + (yy >> 1) * 8448 + xg * 1024)] = f2bf(v);
        }
    }
  }
  __syncthreads();

#pragma unroll
  for (int gx = 0; gx < 4; ++gx) {
    bf16x8 At[4][3];
#pragma unroll
    for (int rr = 0; rr < 4; ++rr)
#pragma unroll
      for (int kx = 0; kx < 3; ++kx)
        At[rr][kx] = *(const bf16x8*)&u2t[rdT[rr][kx] + gx * 512];
    f32x4 acc[2];
#pragma unroll
    for (int r = 0; r < 2; ++r) acc[r] = (f32x4){biast, biast, biast, biast};
    __builtin_amdgcn_s_setprio(1);
#pragma unroll
    for (int ky = 0; ky < 3; ++ky)
#pragma unroll
      for (int kx = 0; kx < 3; ++kx)
#pragma unroll
        for (int r = 0; r < 2; ++r)
          acc[r] = mfma16(At[r + ky][kx], Bt[ky * 3 + kx], acc[r]);
    __builtin_amdgcn_s_setprio(0);
    if (col < 3) {
#pragma unroll
      for (int r = 0; r < 2; ++r) {
        int grow = 8 * b + w * 2 + r;
        int gcol = 64 * xh2 + gx * 16 + s4 * 4;
        *(float4*)&out[(((size_t)img * 3 + col) * 128 + grow) * 128 + gcol] =
            make_float4(acc[r][0], acc[r][1], acc[r][2], acc[r][3]);
      }
    }
  }
}

extern "C" void kernel_launch(void* const* d_in, const int* in_sizes, int n_in,
                              void* d_out, int out_size, void* d_ws, size_t ws_size,
                              hipStream_t stream) {
  const float* inputs = (const float*)d_in[0];
  const float* cls_w = (const float*)d_in[1];
  const float* cls_b = (const float*)d_in[2];
  const float* cls_fw = (const float*)d_in[3];
  const float* cls_fb = (const float*)d_in[4];
  const float* head_w = (const float*)d_in[5];
  const float* head_b = (const float*)d_in[6];
  const float* rb_w1 = (const float*)d_in[7];
  const float* rb_b1 = (const float*)d_in[8];
  const float* rb_w2 = (const float*)d_in[9];
  const float* rb_b2 = (const float*)d_in[10];
  const float* end_w = (const float*)d_in[11];
  const float* end_b = (const float*)d_in[12];
  const float* up_w1 = (const float*)d_in[13];
  const float* up_b1 = (const float*)d_in[14];
  const float* up_w2 = (const float*)d_in[15];
  const float* up_b2 = (const float*)d_in[16];
  const float* tail_w = (const float*)d_in[17];
  const float* tail_b = (const float*)d_in[18];
  float* out = (float*)d_out;
  char* ws = (char*)d_ws;

  int N = in_sizes[0] / 3072;  // 128

  int* slot_img = (int*)(ws + 512);
  float* part = (float*)(ws + 4096);                     // [N][4][32]
  unsigned short* wt = (unsigned short*)(ws + 131072);   // 1.26 MB transformed weights
  const size_t ABUF = (size_t)NSLOT * 1024 * 32 * 2;     // 12,582,912
  size_t o_h = 1572864;
  unsigned short* h = (unsigned short*)(ws + o_h);
  unsigned short* u1 = (unsigned short*)(ws + o_h + ABUF);

  k_cls_conv<<<dim3(4, N), 256, 0, stream>>>(
      inputs, cls_w, cls_b, part, (float4*)out, out_size / 4,
      rb_w1, rb_w2, end_w, up_w1, up_w2, tail_w, wt);
  k_score_route<<<1, 256, 0, stream>>>(part, cls_fw, cls_fb, slot_img, N);

  k_head<<<dim3(4, NSLOT), 256, 0, stream>>>(inputs, h, head_w, head_b, slot_img);

  k_body<<<NSLOT, 512, 0, stream>>>(h, u1, wt, rb_b1, rb_b2, end_b, up_b1, slot_img);

  k_uptail<<<dim3(32, NSLOT), 256, 0, stream>>>(u1, out, wt, up_b2, tail_b, slot_img);
}